// Round 2
// baseline (97753.967 us; speedup 1.0000x reference)
//
#include <hip/hip_runtime.h>
#include <cstdint>
#include <cfloat>

// Fixed dataset: B=512, D=128, N=1M, E=50, K=100
#define NQ     512
#define DIM    128
#define NCAND  1048576
#define TOPK   150        // adjusted k = K + E
#define KOUT   100
#define NEXCL  50
#define STATE_STRIDE 160
#define C0     65536      // exact-pass chunk establishing thresholds
#define CAP    3944       // survivor capacity/query (150+CAP <= 4096 pool)
#define MPOOL  2048       // topk_merge pool
#define FPOOL  4096       // final merge pool

// ---------------------------------------------------------------------------
// 64q x 64c fp32 tile GEMM core. K staged in 2 halves of 64 -> 32 KB LDS
// (4 blocks/CU). XOR swizzle: A fragment reads conflict-free (4 bank-groups),
// B fragment reads 2-way. 4x4 microtile per thread, 256 threads.
// ---------------------------------------------------------------------------
__device__ __forceinline__ void tile_gemm(
    const float* __restrict__ q, const float* __restrict__ cand,
    int q0, int crow0, float* As, float* Bs, int t, float acc[4][4])
{
  const int tm = t >> 4, tn = t & 15;
#pragma unroll
  for (int m = 0; m < 4; ++m)
#pragma unroll
    for (int n = 0; n < 4; ++n) acc[m][n] = 0.f;

#pragma unroll
  for (int h = 0; h < 2; ++h) {
    __syncthreads();   // protect LDS reuse between halves (no-op cost at h=0)
#pragma unroll
    for (int iter = 0; iter < 4; ++iter) {
      int idx = iter * 256 + t;
      int row = idx >> 4;                  // 0..63
      int c4  = idx & 15;                  // 0..15 float4 column
      int sw  = c4 ^ ((row >> 2) & 7);     // XOR swizzle
      float4 av = *(const float4*)(q + (size_t)(q0 + row) * DIM + h * 64 + c4 * 4);
      *(float4*)(As + row * 64 + sw * 4) = av;
      float4 bv = *(const float4*)(cand + (size_t)(crow0 + row) * DIM + h * 64 + c4 * 4);
      *(float4*)(Bs + row * 64 + sw * 4) = bv;
    }
    __syncthreads();
#pragma unroll
    for (int k4 = 0; k4 < 16; ++k4) {
      float4 a[4], b[4];
#pragma unroll
      for (int m = 0; m < 4; ++m)
        a[m] = *(const float4*)(As + (4 * tm + m) * 64 + ((k4 ^ (tm & 7)) * 4));
#pragma unroll
      for (int n = 0; n < 4; ++n)
        b[n] = *(const float4*)(Bs + (4 * tn + n) * 64 + ((k4 ^ (tn & 7)) * 4));
#pragma unroll
      for (int m = 0; m < 4; ++m)
#pragma unroll
        for (int n = 0; n < 4; ++n) {
          acc[m][n] += a[m].x * b[n].x;
          acc[m][n] += a[m].y * b[n].y;
          acc[m][n] += a[m].z * b[n].z;
          acc[m][n] += a[m].w * b[n].w;
        }
    }
  }
}

// ---------------------------------------------------------------------------
// Kernel A0: exact GEMM for chunk0 -> S. grid(8, C/64), x = query tile
// (fastest) so 8 blocks sharing a candidate tile run concurrently (L2 reuse).
// ---------------------------------------------------------------------------
__global__ __launch_bounds__(256, 4) void score_gemm(
    const float* __restrict__ q, const float* __restrict__ cand,
    float* __restrict__ S, int cand_base, int C)
{
  __shared__ float As[64 * 64];
  __shared__ float Bs[64 * 64];
  const int t  = threadIdx.x;
  const int q0 = blockIdx.x * 64;
  const int c0 = blockIdx.y * 64;
  float acc[4][4];
  tile_gemm(q, cand, q0, cand_base + c0, As, Bs, t, acc);

  const int tm = t >> 4, tn = t & 15;
#pragma unroll
  for (int m = 0; m < 4; ++m) {
    float4 v = make_float4(acc[m][0], acc[m][1], acc[m][2], acc[m][3]);
    *(float4*)(S + (size_t)(q0 + 4 * tm + m) * C + c0 + 4 * tn) = v;
  }
}

// ---------------------------------------------------------------------------
// Kernel A1: fused GEMM + threshold filter over the tail candidates.
// Strict '>' is exact: reference ties lose to incumbents, and tau only
// grows after chunk0 — equal-to-tau candidates can never enter the top-150.
// ---------------------------------------------------------------------------
__global__ __launch_bounds__(256, 4) void fused_gemm_filter(
    const float* __restrict__ q, const float* __restrict__ cand,
    const float* __restrict__ tau,
    float* __restrict__ sv_s, int* __restrict__ sv_i, int* __restrict__ cnt,
    int cand_base)
{
  __shared__ float As[64 * 64];
  __shared__ float Bs[64 * 64];
  const int t  = threadIdx.x;
  const int q0 = blockIdx.x * 64;
  const int c0 = cand_base + blockIdx.y * 64;
  float acc[4][4];
  tile_gemm(q, cand, q0, c0, As, Bs, t, acc);

  const int tm = t >> 4, tn = t & 15;
  float tq[4];
#pragma unroll
  for (int m = 0; m < 4; ++m) tq[m] = tau[q0 + 4 * tm + m];
#pragma unroll
  for (int m = 0; m < 4; ++m) {
    int qq = q0 + 4 * tm + m;
#pragma unroll
    for (int n = 0; n < 4; ++n) {
      float v = acc[m][n];
      if (v > tq[m]) {
        int p = atomicAdd(&cnt[qq], 1);
        if (p < CAP) {
          sv_s[(size_t)qq * CAP + p] = v;
          sv_i[(size_t)qq * CAP + p] = c0 + 4 * tn + n;
        }
      }
    }
  }
}

// ---------------------------------------------------------------------------
// Bitonic sort, descending (score desc, id asc). N power of 2, 256 threads.
// ---------------------------------------------------------------------------
template <int N>
__device__ inline void bitonic_sort_desc(float* ps, int* pi, int t)
{
  for (int size = 2; size <= N; size <<= 1) {
    for (int stride = size >> 1; stride > 0; stride >>= 1) {
      __syncthreads();
      for (int i = t; i < N / 2; i += 256) {
        int idx = 2 * i - (i & (stride - 1));
        int j   = idx + stride;
        bool desc = ((idx & size) == 0);
        float s1 = ps[idx], s2 = ps[j];
        int   i1 = pi[idx], i2 = pi[j];
        bool jBetter = (s2 > s1) || (s2 == s1 && i2 < i1);
        if (jBetter == desc) {
          ps[idx] = s2; ps[j] = s1;
          pi[idx] = i2; pi[j] = i1;
        }
      }
    }
  }
  __syncthreads();
}

// ---------------------------------------------------------------------------
// Kernel B: per-query exact top-150 over chunk0 scores; emits tau.
// ---------------------------------------------------------------------------
__global__ __launch_bounds__(256) void topk_merge(
    const float* __restrict__ S,
    float* __restrict__ st_s, int* __restrict__ st_i, float* __restrict__ tau,
    int cand_base, int C)
{
  __shared__ float ps[MPOOL];
  __shared__ int   pi[MPOOL];
  __shared__ int   cnt;
  __shared__ float thr;
  const int b = blockIdx.x;
  const int t = threadIdx.x;

  if (t == 0) { cnt = 0; thr = -FLT_MAX; }
  __syncthreads();

  const float4* row = (const float4*)(S + (size_t)b * C);
  const int nIter = C >> 10;
  for (int it = 0; it < nIter; ++it) {
    if (cnt + 1024 > MPOOL) {
      int c = cnt;
      for (int i = t; i < MPOOL; i += 256)
        if (i >= c) { ps[i] = -FLT_MAX; pi[i] = 0x7fffffff; }
      __syncthreads();
      bitonic_sort_desc<MPOOL>(ps, pi, t);
      if (t == 0) { cnt = (c < TOPK) ? c : TOPK; thr = ps[TOPK - 1]; }
      __syncthreads();
    }
    float4 v = row[it * 256 + t];
    int base_id = cand_base + it * 1024 + t * 4;
    float sv[4] = {v.x, v.y, v.z, v.w};
#pragma unroll
    for (int jj = 0; jj < 4; ++jj) {
      if (sv[jj] > thr) {
        int p = atomicAdd(&cnt, 1);
        ps[p] = sv[jj];
        pi[p] = base_id + jj;
      }
    }
    __syncthreads();
  }
  {
    int c = cnt;
    for (int i = t; i < MPOOL; i += 256)
      if (i >= c) { ps[i] = -FLT_MAX; pi[i] = 0x7fffffff; }
    __syncthreads();
    bitonic_sort_desc<MPOOL>(ps, pi, t);
  }
  if (t < TOPK) {
    st_s[(size_t)b * STATE_STRIDE + t] = ps[t];
    st_i[(size_t)b * STATE_STRIDE + t] = pi[t];
  }
  if (t == 0) tau[b] = ps[TOPK - 1];
}

// ---------------------------------------------------------------------------
// Kernel C: merge chunk0 state + survivors -> exact top-150 per query.
// ---------------------------------------------------------------------------
__global__ __launch_bounds__(256) void final_merge(
    float* __restrict__ st_s, int* __restrict__ st_i,
    const float* __restrict__ sv_s, const int* __restrict__ sv_i,
    const int* __restrict__ cnt)
{
  __shared__ float ps[FPOOL];
  __shared__ int   pi[FPOOL];
  const int b = blockIdx.x;
  const int t = threadIdx.x;
  int c = cnt[b];
  if (c > CAP) c = CAP;

  for (int i = t; i < FPOOL; i += 256) {
    if (i < TOPK) {
      ps[i] = st_s[(size_t)b * STATE_STRIDE + i];
      pi[i] = st_i[(size_t)b * STATE_STRIDE + i];
    } else if (i - TOPK < c) {
      ps[i] = sv_s[(size_t)b * CAP + (i - TOPK)];
      pi[i] = sv_i[(size_t)b * CAP + (i - TOPK)];
    } else {
      ps[i] = -FLT_MAX;
      pi[i] = 0x7fffffff;
    }
  }
  __syncthreads();
  bitonic_sort_desc<FPOOL>(ps, pi, t);
  if (t < TOPK) {
    st_s[(size_t)b * STATE_STRIDE + t] = ps[t];
    st_i[(size_t)b * STATE_STRIDE + t] = pi[t];
  }
}

// ---------------------------------------------------------------------------
// Kernel D: exclusions -> stable top-100 -> out (scores, then ids-as-float).
// ---------------------------------------------------------------------------
__global__ __launch_bounds__(256) void finalize(
    const float* __restrict__ st_s, const int* __restrict__ st_i,
    const int* __restrict__ excl, float* __restrict__ out)
{
  const int b = blockIdx.x;
  const int t = threadIdx.x;
  __shared__ int ex[NEXCL];
  __shared__ unsigned char keep[TOPK];
  __shared__ short pos[TOPK];

  if (t < NEXCL) ex[t] = excl[(size_t)b * NEXCL + t];
  __syncthreads();
  if (t < TOPK) {
    int id = st_i[(size_t)b * STATE_STRIDE + t];
    bool k = true;
#pragma unroll
    for (int j = 0; j < NEXCL; ++j) k = k && (id != ex[j]);
    keep[t] = (unsigned char)k;
  }
  __syncthreads();
  if (t == 0) {
    int p = 0;
    for (int i = 0; i < TOPK; ++i) {
      pos[i] = (keep[i] && p < KOUT) ? (short)p : (short)-1;
      if (keep[i]) ++p;
    }
  }
  __syncthreads();
  if (t < TOPK) {
    int p = pos[t];
    if (p >= 0) {
      out[(size_t)b * KOUT + p] = st_s[(size_t)b * STATE_STRIDE + t];
      out[(size_t)NQ * KOUT + (size_t)b * KOUT + p] =
          (float)st_i[(size_t)b * STATE_STRIDE + t];
    }
  }
}

__global__ void zero_cnt(int* cnt)
{
  int i = blockIdx.x * 256 + threadIdx.x;
  if (i < NQ) cnt[i] = 0;
}

// ---------------------------------------------------------------------------
extern "C" void kernel_launch(void* const* d_in, const int* in_sizes, int n_in,
                              void* d_out, int out_size, void* d_ws, size_t ws_size,
                              hipStream_t stream)
{
  (void)in_sizes; (void)n_in; (void)out_size; (void)ws_size;
  const float* q    = (const float*)d_in[0];
  const float* cand = (const float*)d_in[1];
  const int*   excl = (const int*)d_in[3];
  float* out = (float*)d_out;

  // ws layout (all offsets multiples of 2048B)
  char* w = (char*)d_ws;
  float* st_s = (float*)(w);                                    // 327,680 B
  int*   st_i = (int*)  (w + 327680);                           // 327,680 B
  float* tau  = (float*)(w + 655360);                           //   2,048 B
  int*   cnt  = (int*)  (w + 657408);                           //   2,048 B
  float* sv_s = (float*)(w + 659456);                           // NQ*CAP*4
  int*   sv_i = (int*)  (w + 659456 + (size_t)NQ * CAP * 4);
  float* S    = (float*)(w + 659456 + (size_t)NQ * CAP * 8);    // NQ*C0*4

  zero_cnt<<<2, 256, 0, stream>>>(cnt);
  // Exact pass on chunk0 -> thresholds
  score_gemm<<<dim3(NQ / 64, C0 / 64), 256, 0, stream>>>(q, cand, S, 0, C0);
  topk_merge<<<NQ, 256, 0, stream>>>(S, st_s, st_i, tau, 0, C0);
  // Fused filter pass over the remaining candidates
  fused_gemm_filter<<<dim3(NQ / 64, (NCAND - C0) / 64), 256, 0, stream>>>(
      q, cand, tau, sv_s, sv_i, cnt, C0);
  // Exact top-150 from state + survivors, then exclusions
  final_merge<<<NQ, 256, 0, stream>>>(st_s, st_i, sv_s, sv_i, cnt);
  finalize<<<NQ, 256, 0, stream>>>(st_s, st_i, excl, out);
}